// Round 1
// baseline (1876.389 us; speedup 1.0000x reference)
//
#include <hip/hip_runtime.h>
#include <cstdint>

#define D_MODEL 1024
#define D_INNER 2048
#define NSTATE  16
#define DT_RANK 64
#define SEQ     2048
#define NBATCH  2
#define NTOK    (NBATCH * SEQ)   // 4096

typedef float  f32x4  __attribute__((ext_vector_type(4)));
typedef __bf16 bf16x8 __attribute__((ext_vector_type(8)));
typedef short  s16x8  __attribute__((ext_vector_type(8)));

__device__ __forceinline__ unsigned short f2bf(float f) {
  union { float f; uint32_t u; } a; a.f = f;
  uint32_t u = a.u;
  uint32_t r = (u + 0x7FFFu + ((u >> 16) & 1u)) >> 16;
  return (unsigned short)r;
}
__device__ __forceinline__ float bf2f(unsigned short h) {
  union { uint32_t u; float f; } a; a.u = ((uint32_t)h) << 16;
  return a.f;
}

__device__ __forceinline__ void gload16(const void* g, void* l) {
  __builtin_amdgcn_global_load_lds((__attribute__((address_space(1))) void*)g,
                                   (__attribute__((address_space(3))) void*)l,
                                   16, 0, 0);
}

// ---------------- RMSNorm + cast to bf16 ----------------
__global__ __launch_bounds__(256) void rmsnorm_kernel(const float* __restrict__ x,
                                                      const float* __restrict__ nw,
                                                      unsigned short* __restrict__ xn) {
  const int row = blockIdx.x;
  const float4 v = ((const float4*)(x + (size_t)row * D_MODEL))[threadIdx.x];
  float ss = v.x*v.x + v.y*v.y + v.z*v.z + v.w*v.w;
  #pragma unroll
  for (int m = 32; m; m >>= 1) ss += __shfl_xor(ss, m);
  __shared__ float red[4];
  if ((threadIdx.x & 63) == 0) red[threadIdx.x >> 6] = ss;
  __syncthreads();
  const float tot = red[0] + red[1] + red[2] + red[3];
  const float rs = rsqrtf(tot * (1.0f / D_MODEL) + 1e-5f);
  const float4 w = ((const float4*)nw)[threadIdx.x];
  ushort4 o;
  o.x = f2bf(v.x * rs * w.x);
  o.y = f2bf(v.y * rs * w.y);
  o.z = f2bf(v.z * rs * w.z);
  o.w = f2bf(v.w * rs * w.w);
  ((ushort4*)(xn + (size_t)row * D_MODEL))[threadIdx.x] = o;
}

// ---------------- transpose W[K][N] f32 -> Wt[Npad][K] bf16 (zero-pad rows N..Npad) ----
__global__ __launch_bounds__(256) void transpose_cast_kernel(const float* __restrict__ W,
                                                             unsigned short* __restrict__ Wt,
                                                             int K, int N, int Npad) {
  __shared__ float tile[32][33];
  const int tx = threadIdx.x & 31, ty = threadIdx.x >> 5;
  const int kt = blockIdx.y * 32, nt = blockIdx.x * 32;
  #pragma unroll
  for (int i = 0; i < 4; ++i) {
    const int k = kt + ty + i*8, n = nt + tx;
    tile[ty + i*8][tx] = (k < K && n < N) ? W[(size_t)k * N + n] : 0.0f;
  }
  __syncthreads();
  #pragma unroll
  for (int i = 0; i < 4; ++i) {
    const int n = nt + ty + i*8, k = kt + tx;
    if (n < Npad && k < K) Wt[(size_t)n * K + k] = f2bf(tile[tx][ty + i*8]);
  }
}

// ---------------- GEMM: C[M][N] = A[M][K] @ Bt[N][K]^T  (bf16 in, fp32 acc) ----------
// MODE 0: split -> xi_raw bf16 (col<2048), res bf16 (col>=2048). N=4096
// MODE 1: col<64 -> delta_r bf16 [M][64]; 64<=col<96 -> BC f32 [M][32]; else skip. N=128(pad)
// MODE 2: softplus(v + dt_b[col]) -> delta bf16 [M][2048]. N=2048
// MODE 3: v + x[row][col] -> out f32 [M][1024]. N=1024
template<int MODE>
__global__ __launch_bounds__(256) void gemm_bt_kernel(const unsigned short* __restrict__ A,
                                                      const unsigned short* __restrict__ Bt,
                                                      const int M, const int N, const int K,
                                                      void* __restrict__ out0,
                                                      void* __restrict__ out1,
                                                      const float* __restrict__ extra) {
  __shared__ __align__(16) unsigned short sA[128 * 32];
  __shared__ __align__(16) unsigned short sB[128 * 32];
  const int tid = threadIdx.x;
  const int w = tid >> 6, lane = tid & 63;
  const int m0 = blockIdx.y * 128, n0 = blockIdx.x * 128;
  const int wm = w >> 1, wn = w & 1;
  const int lr = lane & 15, kq = lane >> 4;

  f32x4 acc[4][4] = {};

  // staging: LDS chunk p=(row,qlds) holds global (row, qlds ^ (row&3))  [4-way-conflict swizzle]
  const int r0 = tid >> 2;
  const int qb = ((tid & 3) ^ (r0 & 3)) * 16;      // source byte-in-row (swizzle-inverse)
  const char* pA0 = (const char*)A + ((size_t)(m0 + r0)      * K) * 2 + qb;
  const char* pA1 = (const char*)A + ((size_t)(m0 + r0 + 64) * K) * 2 + qb;
  const char* pB0 = (const char*)Bt + ((size_t)(n0 + r0)      * K) * 2 + qb;
  const char* pB1 = (const char*)Bt + ((size_t)(n0 + r0 + 64) * K) * 2 + qb;
  char* ldsA0 = (char*)sA + w * 1024;
  char* ldsA1 = (char*)sA + 4096 + w * 1024;
  char* ldsB0 = (char*)sB + w * 1024;
  char* ldsB1 = (char*)sB + 4096 + w * 1024;

  // fragment read pointers (swizzled quarter)
  const int kqs = (kq ^ (lr & 3)) * 8;
  const unsigned short* pa = sA + (wm*64 + lr) * 32 + kqs;
  const unsigned short* pb = sB + (wn*64 + lr) * 32 + kqs;

  for (int k0 = 0; k0 < K; k0 += 32) {
    __syncthreads();
    gload16(pA0 + (size_t)k0 * 2, ldsA0);
    gload16(pA1 + (size_t)k0 * 2, ldsA1);
    gload16(pB0 + (size_t)k0 * 2, ldsB0);
    gload16(pB1 + (size_t)k0 * 2, ldsB1);
    __syncthreads();
    bf16x8 af[4], bb[4];
    #pragma unroll
    for (int mf = 0; mf < 4; ++mf)
      af[mf] = __builtin_bit_cast(bf16x8, *(const s16x8*)(pa + mf * 16 * 32));
    #pragma unroll
    for (int nf = 0; nf < 4; ++nf)
      bb[nf] = __builtin_bit_cast(bf16x8, *(const s16x8*)(pb + nf * 16 * 32));
    #pragma unroll
    for (int mf = 0; mf < 4; ++mf)
      #pragma unroll
      for (int nf = 0; nf < 4; ++nf)
        acc[mf][nf] = __builtin_amdgcn_mfma_f32_16x16x32_bf16(af[mf], bb[nf], acc[mf][nf], 0, 0, 0);
  }

  #pragma unroll
  for (int mf = 0; mf < 4; ++mf) {
    #pragma unroll
    for (int nf = 0; nf < 4; ++nf) {
      #pragma unroll
      for (int r = 0; r < 4; ++r) {
        const int row = m0 + wm*64 + mf*16 + kq*4 + r;
        const int col = n0 + wn*64 + nf*16 + lr;
        const float v = acc[mf][nf][r];
        if constexpr (MODE == 0) {
          if (col < D_INNER) ((unsigned short*)out0)[(size_t)row * D_INNER + col] = f2bf(v);
          else               ((unsigned short*)out1)[(size_t)row * D_INNER + (col - D_INNER)] = f2bf(v);
        } else if constexpr (MODE == 1) {
          if (col < DT_RANK) ((unsigned short*)out0)[(size_t)row * DT_RANK + col] = f2bf(v);
          else if (col < DT_RANK + 2*NSTATE) ((float*)out1)[(size_t)row * (2*NSTATE) + (col - DT_RANK)] = v;
        } else if constexpr (MODE == 2) {
          const float t = v + extra[col];
          const float sp = (t > 20.0f) ? t : log1pf(__expf(t));
          ((unsigned short*)out0)[(size_t)row * D_INNER + col] = f2bf(sp);
        } else {
          ((float*)out0)[(size_t)row * D_MODEL + col] = v + extra[(size_t)row * D_MODEL + col];
        }
      }
    }
  }
}

// ---------------- causal depthwise conv (width 4) + bias + SiLU ----------------
__global__ __launch_bounds__(256) void conv_silu_kernel(const unsigned short* __restrict__ xi_raw,
                                                        const float* __restrict__ cw,
                                                        const float* __restrict__ cb,
                                                        unsigned short* __restrict__ xi) {
  const int t = blockIdx.x * 256 + threadIdx.x;   // NTOK*1024 threads, 2 channels each
  const int d2 = (t & 1023) * 2;
  const int row = t >> 10;                        // b*SEQ + l
  const int l = row & (SEQ - 1);
  float a0 = cb[d2], a1 = cb[d2 + 1];
  #pragma unroll
  for (int tap = 0; tap < 4; ++tap) {
    const int lp = l - 3 + tap;
    if (lp >= 0) {
      const uint32_t u = *(const uint32_t*)(xi_raw + (size_t)(row - 3 + tap) * D_INNER + d2);
      a0 += cw[d2 * 4 + tap]       * bf2f((unsigned short)(u & 0xFFFFu));
      a1 += cw[(d2 + 1) * 4 + tap] * bf2f((unsigned short)(u >> 16));
    }
  }
  a0 = a0 / (1.0f + __expf(-a0));
  a1 = a1 / (1.0f + __expf(-a1));
  const uint32_t o = (uint32_t)f2bf(a0) | ((uint32_t)f2bf(a1) << 16);
  *(uint32_t*)(xi + (size_t)row * D_INNER + d2) = o;
}

// ---------------- selective scan + skip + gate, fused ----------------
// block: 256 thr = 16 channels x 16 states. grid: NBATCH * D_INNER/16 = 256
__global__ __launch_bounds__(256) void scan_kernel(const unsigned short* __restrict__ delta,
                                                   const unsigned short* __restrict__ xi,
                                                   const unsigned short* __restrict__ res,
                                                   const float* __restrict__ BC,
                                                   const float* __restrict__ A_log,
                                                   const float* __restrict__ Dv,
                                                   unsigned short* __restrict__ yg) {
  const int b  = blockIdx.x >> 7;
  const int d0 = (blockIdx.x & 127) * 16;
  const int ci = threadIdx.x >> 4;
  const int n  = threadIdx.x & 15;
  const int d  = d0 + ci;
  const float Acoef = -expf(A_log[d * NSTATE + n]);
  const float Dd = Dv[d];
  float state = 0.0f;
  const size_t base = (size_t)b * SEQ;
  for (int l = 0; l < SEQ; ++l) {
    const size_t row = base + l;
    const float dlt = bf2f(delta[row * D_INNER + d]);
    const float u   = bf2f(xi[row * D_INNER + d]);
    const float Bn  = BC[row * 32 + n];
    const float Cn  = BC[row * 32 + 16 + n];
    const float dA  = __expf(dlt * Acoef);
    state = dA * state + dlt * Bn * u;
    float y = state * Cn;
    y += __shfl_xor(y, 8);
    y += __shfl_xor(y, 4);
    y += __shfl_xor(y, 2);
    y += __shfl_xor(y, 1);
    if (n == 0) {
      const float r = bf2f(res[row * D_INNER + d]);
      float o = y + u * Dd;
      o *= r / (1.0f + __expf(-r));
      yg[row * D_INNER + d] = f2bf(o);
    }
  }
}

// ---------------- launcher ----------------
extern "C" void kernel_launch(void* const* d_in, const int* in_sizes, int n_in,
                              void* d_out, int out_size, void* d_ws, size_t ws_size,
                              hipStream_t stream) {
  const float* x        = (const float*)d_in[0];
  const float* in_proj  = (const float*)d_in[1];
  const float* conv_w   = (const float*)d_in[2];
  const float* conv_b   = (const float*)d_in[3];
  const float* x_proj   = (const float*)d_in[4];
  const float* dt_proj  = (const float*)d_in[5];
  const float* dt_b     = (const float*)d_in[6];
  const float* A_log    = (const float*)d_in[7];
  const float* Dv       = (const float*)d_in[8];
  const float* out_proj = (const float*)d_in[9];
  const float* norm_w   = (const float*)d_in[10];

  char* ws = (char*)d_ws;
  size_t off = 0;
  auto alloc = [&](size_t bytes) {
    char* p = ws + off; off += (bytes + 255) & ~(size_t)255; return p;
  };
  unsigned short* xn     = (unsigned short*)alloc((size_t)NTOK * D_MODEL * 2);
  unsigned short* W1t    = (unsigned short*)alloc((size_t)(2 * D_INNER) * D_MODEL * 2);
  unsigned short* xi_raw = (unsigned short*)alloc((size_t)NTOK * D_INNER * 2);
  unsigned short* resb   = (unsigned short*)alloc((size_t)NTOK * D_INNER * 2);
  unsigned short* xi     = (unsigned short*)alloc((size_t)NTOK * D_INNER * 2);
  unsigned short* W2t    = (unsigned short*)alloc((size_t)128 * D_INNER * 2);
  unsigned short* dr     = (unsigned short*)alloc((size_t)NTOK * DT_RANK * 2);
  float*          BC     = (float*)alloc((size_t)NTOK * 32 * 4);
  unsigned short* W3t    = (unsigned short*)alloc((size_t)D_INNER * DT_RANK * 2);
  unsigned short* dlt    = (unsigned short*)alloc((size_t)NTOK * D_INNER * 2);
  unsigned short* ygb    = (unsigned short*)alloc((size_t)NTOK * D_INNER * 2);
  unsigned short* W4t    = (unsigned short*)alloc((size_t)D_MODEL * D_INNER * 2);

  rmsnorm_kernel<<<NTOK, 256, 0, stream>>>(x, norm_w, xn);
  transpose_cast_kernel<<<dim3(4096/32, 1024/32), 256, 0, stream>>>(in_proj, W1t, 1024, 4096, 4096);
  transpose_cast_kernel<<<dim3(128/32, 2048/32), 256, 0, stream>>>(x_proj, W2t, 2048, 96, 128);
  transpose_cast_kernel<<<dim3(2048/32, 64/32), 256, 0, stream>>>(dt_proj, W3t, 64, 2048, 2048);
  transpose_cast_kernel<<<dim3(1024/32, 2048/32), 256, 0, stream>>>(out_proj, W4t, 2048, 1024, 1024);

  gemm_bt_kernel<0><<<dim3(4096/128, 4096/128), 256, 0, stream>>>(xn, W1t, NTOK, 4096, 1024, xi_raw, resb, nullptr);
  conv_silu_kernel<<<(NTOK * 1024) / 256, 256, 0, stream>>>(xi_raw, conv_w, conv_b, xi);
  gemm_bt_kernel<1><<<dim3(1, 4096/128), 256, 0, stream>>>(xi, W2t, NTOK, 128, 2048, dr, BC, nullptr);
  gemm_bt_kernel<2><<<dim3(2048/128, 4096/128), 256, 0, stream>>>(dr, W3t, NTOK, 2048, 64, dlt, nullptr, dt_b);
  scan_kernel<<<NBATCH * (D_INNER / 16), 256, 0, stream>>>(dlt, xi, resb, BC, A_log, Dv, ygb);
  gemm_bt_kernel<3><<<dim3(1024/128, 4096/128), 256, 0, stream>>>(ygb, W4t, NTOK, 1024, 2048, d_out, nullptr, x);
}

// Round 3
// 442.372 us; speedup vs baseline: 4.2417x; 4.2417x over previous
//
#include <hip/hip_runtime.h>
#include <cstdint>

#define D_MODEL 1024
#define D_INNER 2048
#define NSTATE  16
#define DT_RANK 64
#define SEQ     2048
#define NBATCH  2
#define NTOK    (NBATCH * SEQ)   // 4096

// chunked scan
#define NC      32               // chunks per sequence
#define CHK     64               // steps per chunk (NC*CHK == SEQ)
#define NGRP    8                // groups of 8 steps per chunk

typedef float  f32x4  __attribute__((ext_vector_type(4)));
typedef __bf16 bf16x8 __attribute__((ext_vector_type(8)));
typedef short  s16x8  __attribute__((ext_vector_type(8)));

__device__ __forceinline__ unsigned short f2bf(float f) {
  union { float f; uint32_t u; } a; a.f = f;
  uint32_t u = a.u;
  uint32_t r = (u + 0x7FFFu + ((u >> 16) & 1u)) >> 16;
  return (unsigned short)r;
}
__device__ __forceinline__ float bf2f(unsigned short h) {
  union { uint32_t u; float f; } a; a.u = ((uint32_t)h) << 16;
  return a.f;
}

__device__ __forceinline__ void gload16(const void* g, void* l) {
  __builtin_amdgcn_global_load_lds((__attribute__((address_space(1))) void*)g,
                                   (__attribute__((address_space(3))) void*)l,
                                   16, 0, 0);
}

// ---------------- RMSNorm + cast to bf16 ----------------
__global__ __launch_bounds__(256) void rmsnorm_kernel(const float* __restrict__ x,
                                                      const float* __restrict__ nw,
                                                      unsigned short* __restrict__ xn) {
  const int row = blockIdx.x;
  const float4 v = ((const float4*)(x + (size_t)row * D_MODEL))[threadIdx.x];
  float ss = v.x*v.x + v.y*v.y + v.z*v.z + v.w*v.w;
  #pragma unroll
  for (int m = 32; m; m >>= 1) ss += __shfl_xor(ss, m);
  __shared__ float red[4];
  if ((threadIdx.x & 63) == 0) red[threadIdx.x >> 6] = ss;
  __syncthreads();
  const float tot = red[0] + red[1] + red[2] + red[3];
  const float rs = rsqrtf(tot * (1.0f / D_MODEL) + 1e-5f);
  const float4 w = ((const float4*)nw)[threadIdx.x];
  ushort4 o;
  o.x = f2bf(v.x * rs * w.x);
  o.y = f2bf(v.y * rs * w.y);
  o.z = f2bf(v.z * rs * w.z);
  o.w = f2bf(v.w * rs * w.w);
  ((ushort4*)(xn + (size_t)row * D_MODEL))[threadIdx.x] = o;
}

// ---------------- transpose W[K][N] f32 -> Wt[Npad][K] bf16 (zero-pad rows N..Npad) ----
__global__ __launch_bounds__(256) void transpose_cast_kernel(const float* __restrict__ W,
                                                             unsigned short* __restrict__ Wt,
                                                             int K, int N, int Npad) {
  __shared__ float tile[32][33];
  const int tx = threadIdx.x & 31, ty = threadIdx.x >> 5;
  const int kt = blockIdx.y * 32, nt = blockIdx.x * 32;
  #pragma unroll
  for (int i = 0; i < 4; ++i) {
    const int k = kt + ty + i*8, n = nt + tx;
    tile[ty + i*8][tx] = (k < K && n < N) ? W[(size_t)k * N + n] : 0.0f;
  }
  __syncthreads();
  #pragma unroll
  for (int i = 0; i < 4; ++i) {
    const int n = nt + ty + i*8, k = kt + tx;
    if (n < Npad && k < K) Wt[(size_t)n * K + k] = f2bf(tile[tx][ty + i*8]);
  }
}

// ---------------- GEMM: C[M][N] = A[M][K] @ Bt[N][K]^T  (bf16 in, fp32 acc) ----------
// MODE 0: split -> xi_raw bf16 (col<2048), res bf16 (col>=2048). N=4096
// MODE 1: col<64 -> delta_r bf16 [M][64]; 64<=col<96 -> BC f32 [M][32]; else skip. N=128(pad)
// MODE 2: softplus(v + dt_b[col]) -> delta bf16 [M][2048]. N=2048
// MODE 3: v + x[row][col] -> out f32 [M][1024]. N=1024
template<int MODE>
__global__ __launch_bounds__(256) void gemm_bt_kernel(const unsigned short* __restrict__ A,
                                                      const unsigned short* __restrict__ Bt,
                                                      const int M, const int N, const int K,
                                                      void* __restrict__ out0,
                                                      void* __restrict__ out1,
                                                      const float* __restrict__ extra) {
  __shared__ __align__(16) unsigned short sA[128 * 32];
  __shared__ __align__(16) unsigned short sB[128 * 32];
  const int tid = threadIdx.x;
  const int w = tid >> 6, lane = tid & 63;
  const int m0 = blockIdx.y * 128, n0 = blockIdx.x * 128;
  const int wm = w >> 1, wn = w & 1;
  const int lr = lane & 15, kq = lane >> 4;

  f32x4 acc[4][4] = {};

  // staging: LDS chunk p=(row,qlds) holds global (row, qlds ^ (row&3))  [4-way-conflict swizzle]
  const int r0 = tid >> 2;
  const int qb = ((tid & 3) ^ (r0 & 3)) * 16;      // source byte-in-row (swizzle-inverse)
  const char* pA0 = (const char*)A + ((size_t)(m0 + r0)      * K) * 2 + qb;
  const char* pA1 = (const char*)A + ((size_t)(m0 + r0 + 64) * K) * 2 + qb;
  const char* pB0 = (const char*)Bt + ((size_t)(n0 + r0)      * K) * 2 + qb;
  const char* pB1 = (const char*)Bt + ((size_t)(n0 + r0 + 64) * K) * 2 + qb;
  char* ldsA0 = (char*)sA + w * 1024;
  char* ldsA1 = (char*)sA + 4096 + w * 1024;
  char* ldsB0 = (char*)sB + w * 1024;
  char* ldsB1 = (char*)sB + 4096 + w * 1024;

  // fragment read pointers (swizzled quarter)
  const int kqs = (kq ^ (lr & 3)) * 8;
  const unsigned short* pa = sA + (wm*64 + lr) * 32 + kqs;
  const unsigned short* pb = sB + (wn*64 + lr) * 32 + kqs;

  for (int k0 = 0; k0 < K; k0 += 32) {
    __syncthreads();
    gload16(pA0 + (size_t)k0 * 2, ldsA0);
    gload16(pA1 + (size_t)k0 * 2, ldsA1);
    gload16(pB0 + (size_t)k0 * 2, ldsB0);
    gload16(pB1 + (size_t)k0 * 2, ldsB1);
    __syncthreads();
    bf16x8 af[4], bb[4];
    #pragma unroll
    for (int mf = 0; mf < 4; ++mf)
      af[mf] = __builtin_bit_cast(bf16x8, *(const s16x8*)(pa + mf * 16 * 32));
    #pragma unroll
    for (int nf = 0; nf < 4; ++nf)
      bb[nf] = __builtin_bit_cast(bf16x8, *(const s16x8*)(pb + nf * 16 * 32));
    #pragma unroll
    for (int mf = 0; mf < 4; ++mf)
      #pragma unroll
      for (int nf = 0; nf < 4; ++nf)
        acc[mf][nf] = __builtin_amdgcn_mfma_f32_16x16x32_bf16(af[mf], bb[nf], acc[mf][nf], 0, 0, 0);
  }

  #pragma unroll
  for (int mf = 0; mf < 4; ++mf) {
    #pragma unroll
    for (int nf = 0; nf < 4; ++nf) {
      #pragma unroll
      for (int r = 0; r < 4; ++r) {
        const int row = m0 + wm*64 + mf*16 + kq*4 + r;
        const int col = n0 + wn*64 + nf*16 + lr;
        const float v = acc[mf][nf][r];
        if constexpr (MODE == 0) {
          if (col < D_INNER) ((unsigned short*)out0)[(size_t)row * D_INNER + col] = f2bf(v);
          else               ((unsigned short*)out1)[(size_t)row * D_INNER + (col - D_INNER)] = f2bf(v);
        } else if constexpr (MODE == 1) {
          if (col < DT_RANK) ((unsigned short*)out0)[(size_t)row * DT_RANK + col] = f2bf(v);
          else if (col < DT_RANK + 2*NSTATE) ((float*)out1)[(size_t)row * (2*NSTATE) + (col - DT_RANK)] = v;
        } else if constexpr (MODE == 2) {
          const float t = v + extra[col];
          const float sp = (t > 20.0f) ? t : log1pf(__expf(t));
          ((unsigned short*)out0)[(size_t)row * D_INNER + col] = f2bf(sp);
        } else {
          ((float*)out0)[(size_t)row * D_MODEL + col] = v + extra[(size_t)row * D_MODEL + col];
        }
      }
    }
  }
}

// ---------------- causal depthwise conv (width 4) + bias + SiLU ----------------
__global__ __launch_bounds__(256) void conv_silu_kernel(const unsigned short* __restrict__ xi_raw,
                                                        const float* __restrict__ cw,
                                                        const float* __restrict__ cb,
                                                        unsigned short* __restrict__ xi) {
  const int t = blockIdx.x * 256 + threadIdx.x;   // NTOK*1024 threads, 2 channels each
  const int d2 = (t & 1023) * 2;
  const int row = t >> 10;                        // b*SEQ + l
  const int l = row & (SEQ - 1);
  float a0 = cb[d2], a1 = cb[d2 + 1];
  #pragma unroll
  for (int tap = 0; tap < 4; ++tap) {
    const int lp = l - 3 + tap;
    if (lp >= 0) {
      const uint32_t u = *(const uint32_t*)(xi_raw + (size_t)(row - 3 + tap) * D_INNER + d2);
      a0 += cw[d2 * 4 + tap]       * bf2f((unsigned short)(u & 0xFFFFu));
      a1 += cw[(d2 + 1) * 4 + tap] * bf2f((unsigned short)(u >> 16));
    }
  }
  a0 = a0 / (1.0f + __expf(-a0));
  a1 = a1 / (1.0f + __expf(-a1));
  const uint32_t o = (uint32_t)f2bf(a0) | ((uint32_t)f2bf(a1) << 16);
  *(uint32_t*)(xi + (size_t)row * D_INNER + d2) = o;
}

// ---------------- chunked selective scan ----------------
// PASS 0: per-chunk summary with s_in=0 -> aprod[16], send[16]  (layout [b][c][d][16] f32)
// PASS 1: replay chunk from initS, fused y = C.s + u*D, gate by silu(res), store yg bf16
// block = 256 threads = 256 channels; grid = NBATCH*NC*(D_INNER/256) = 512
template<int PASS>
__global__ __launch_bounds__(256) void scan_pass_kernel(const unsigned short* __restrict__ delta,
                                                        const unsigned short* __restrict__ xi,
                                                        const unsigned short* __restrict__ res,
                                                        const float* __restrict__ BC,
                                                        const float* __restrict__ A_log,
                                                        const float* __restrict__ Dv,
                                                        const float* __restrict__ initS,
                                                        float* __restrict__ aprodOut,
                                                        float* __restrict__ sendOut,
                                                        unsigned short* __restrict__ yg) {
  const int tid = threadIdx.x;
  const int db = blockIdx.x & 7;
  const int c  = (blockIdx.x >> 3) & (NC - 1);
  const int b  = blockIdx.x >> 8;
  const int d  = db * 256 + tid;
  const int row0 = b * SEQ + c * CHK;
  const size_t ob = ((size_t)(b * NC + c) * D_INNER + d) * 16;

  float Ac[16];
  #pragma unroll
  for (int q = 0; q < 4; ++q) {
    f32x4 t = ((const f32x4*)(A_log + (size_t)d * 16))[q];
    Ac[q*4+0] = -expf(t[0]); Ac[q*4+1] = -expf(t[1]);
    Ac[q*4+2] = -expf(t[2]); Ac[q*4+3] = -expf(t[3]);
  }
  float s[16];
  float ap[16];
  if constexpr (PASS == 0) {
    #pragma unroll
    for (int n = 0; n < 16; ++n) { s[n] = 0.0f; ap[n] = 1.0f; }
  } else {
    #pragma unroll
    for (int q = 0; q < 4; ++q)
      ((f32x4*)s)[q] = ((const f32x4*)(initS + ob))[q];
  }
  float Dd = 0.0f;
  if constexpr (PASS == 1) Dd = Dv[d];

  __shared__ float bcbuf[2][8][32];
  // stage BC rows for group g into parity p
  auto stageg = [&](int g, int p) {
    bcbuf[p][tid >> 5][tid & 31] = BC[(size_t)(row0 + g * 8) * 32 + tid];
  };
  stageg(0, 0);

  for (int g = 0; g < NGRP; ++g) {
    // register-prefetch this group's per-channel inputs (independent of state)
    unsigned short dl[8], uu[8], rr[8];
    #pragma unroll
    for (int j = 0; j < 8; ++j) {
      const size_t row = (size_t)(row0 + g * 8 + j) * D_INNER + d;
      dl[j] = delta[row];
      uu[j] = xi[row];
      if constexpr (PASS == 1) rr[j] = res[row];
    }
    __syncthreads();
    if (g + 1 < NGRP) stageg(g + 1, (g + 1) & 1);

    #pragma unroll
    for (int j = 0; j < 8; ++j) {
      const float dlt = bf2f(dl[j]);
      const float u   = bf2f(uu[j]);
      const float dlu = dlt * u;
      float bc[32];
      #pragma unroll
      for (int q = 0; q < (PASS ? 8 : 4); ++q)
        ((f32x4*)bc)[q] = ((const f32x4*)(&bcbuf[g & 1][j][0]))[q];
      #pragma unroll
      for (int n = 0; n < 16; ++n) {
        const float dA = __expf(dlt * Ac[n]);
        s[n] = dA * s[n] + dlu * bc[n];
        if constexpr (PASS == 0) ap[n] *= dA;
      }
      if constexpr (PASS == 1) {
        float y = 0.0f;
        #pragma unroll
        for (int n = 0; n < 16; ++n) y += s[n] * bc[16 + n];
        const float r = bf2f(rr[j]);
        const float o = (y + u * Dd) * (r / (1.0f + __expf(-r)));
        yg[(size_t)(row0 + g * 8 + j) * D_INNER + d] = f2bf(o);
      }
    }
  }

  if constexpr (PASS == 0) {
    #pragma unroll
    for (int q = 0; q < 4; ++q) {
      ((f32x4*)(aprodOut + ob))[q] = ((f32x4*)ap)[q];
      ((f32x4*)(sendOut + ob))[q]  = ((f32x4*)s)[q];
    }
  }
}

// ---------------- combine chunk summaries: carry_c = state entering chunk c ----------
// float4-per-thread over [b][d][n]; 2*32768/4 = 16384 threads
__global__ __launch_bounds__(256) void scan_combine_kernel(const float* __restrict__ aprod,
                                                           const float* __restrict__ send,
                                                           float* __restrict__ initS) {
  const int t = blockIdx.x * 256 + threadIdx.x;
  const int b = t >> 13;
  const int rq = t & 8191;
  f32x4 carry = {0.0f, 0.0f, 0.0f, 0.0f};
  #pragma unroll
  for (int c = 0; c < NC; ++c) {
    const size_t idx = (size_t)(b * NC + c) * 8192 + rq;
    ((f32x4*)initS)[idx] = carry;
    const f32x4 a = ((const f32x4*)aprod)[idx];
    const f32x4 e = ((const f32x4*)send)[idx];
    carry = a * carry + e;
  }
}

// ---------------- launcher ----------------
extern "C" void kernel_launch(void* const* d_in, const int* in_sizes, int n_in,
                              void* d_out, int out_size, void* d_ws, size_t ws_size,
                              hipStream_t stream) {
  const float* x        = (const float*)d_in[0];
  const float* in_proj  = (const float*)d_in[1];
  const float* conv_w   = (const float*)d_in[2];
  const float* conv_b   = (const float*)d_in[3];
  const float* x_proj   = (const float*)d_in[4];
  const float* dt_proj  = (const float*)d_in[5];
  const float* dt_b     = (const float*)d_in[6];
  const float* A_log    = (const float*)d_in[7];
  const float* Dv       = (const float*)d_in[8];
  const float* out_proj = (const float*)d_in[9];
  const float* norm_w   = (const float*)d_in[10];

  char* ws = (char*)d_ws;
  size_t off = 0;
  auto alloc = [&](size_t bytes) {
    char* p = ws + off; off += (bytes + 255) & ~(size_t)255; return p;
  };
  unsigned short* xn     = (unsigned short*)alloc((size_t)NTOK * D_MODEL * 2);   // 8 MB (reused as initS)
  unsigned short* W1t    = (unsigned short*)alloc((size_t)(2 * D_INNER) * D_MODEL * 2);
  unsigned short* xi_raw = (unsigned short*)alloc((size_t)NTOK * D_INNER * 2);   // 16 MB (reused as aprod+send)
  unsigned short* resb   = (unsigned short*)alloc((size_t)NTOK * D_INNER * 2);
  unsigned short* xi     = (unsigned short*)alloc((size_t)NTOK * D_INNER * 2);
  unsigned short* W2t    = (unsigned short*)alloc((size_t)128 * D_INNER * 2);
  unsigned short* dr     = (unsigned short*)alloc((size_t)NTOK * DT_RANK * 2);
  float*          BC     = (float*)alloc((size_t)NTOK * 32 * 4);
  unsigned short* W3t    = (unsigned short*)alloc((size_t)D_INNER * DT_RANK * 2);
  unsigned short* dlt    = (unsigned short*)alloc((size_t)NTOK * D_INNER * 2);
  unsigned short* ygb    = (unsigned short*)alloc((size_t)NTOK * D_INNER * 2);
  unsigned short* W4t    = (unsigned short*)alloc((size_t)D_MODEL * D_INNER * 2);

  // scan scratch reuses buffers dead by scan time:
  //   aprod/send (8 MB each) overlay xi_raw (16 MB, dead after conv)
  //   initS (8 MB) overlays xn (8 MB, dead after GEMM1)
  float* aprod = (float*)xi_raw;
  float* send  = (float*)((char*)xi_raw + 8388608);
  float* initS = (float*)xn;

  rmsnorm_kernel<<<NTOK, 256, 0, stream>>>(x, norm_w, xn);
  transpose_cast_kernel<<<dim3(4096/32, 1024/32), 256, 0, stream>>>(in_proj, W1t, 1024, 4096, 4096);
  transpose_cast_kernel<<<dim3(128/32, 2048/32), 256, 0, stream>>>(x_proj, W2t, 2048, 96, 128);
  transpose_cast_kernel<<<dim3(2048/32, 64/32), 256, 0, stream>>>(dt_proj, W3t, 64, 2048, 2048);
  transpose_cast_kernel<<<dim3(1024/32, 2048/32), 256, 0, stream>>>(out_proj, W4t, 2048, 1024, 1024);

  gemm_bt_kernel<0><<<dim3(4096/128, 4096/128), 256, 0, stream>>>(xn, W1t, NTOK, 4096, 1024, xi_raw, resb, nullptr);
  conv_silu_kernel<<<(NTOK * 1024) / 256, 256, 0, stream>>>(xi_raw, conv_w, conv_b, xi);
  gemm_bt_kernel<1><<<dim3(1, 4096/128), 256, 0, stream>>>(xi, W2t, NTOK, 128, 2048, dr, BC, nullptr);
  gemm_bt_kernel<2><<<dim3(2048/128, 4096/128), 256, 0, stream>>>(dr, W3t, NTOK, 2048, 64, dlt, nullptr, dt_b);

  scan_pass_kernel<0><<<NBATCH * NC * (D_INNER/256), 256, 0, stream>>>(
      dlt, xi, nullptr, BC, A_log, nullptr, nullptr, aprod, send, nullptr);
  scan_combine_kernel<<<64, 256, 0, stream>>>(aprod, send, initS);
  scan_pass_kernel<1><<<NBATCH * NC * (D_INNER/256), 256, 0, stream>>>(
      dlt, xi, resb, BC, A_log, Dv, initS, nullptr, nullptr, ygb);

  gemm_bt_kernel<3><<<dim3(1024/128, 4096/128), 256, 0, stream>>>(ygb, W4t, NTOK, 1024, 2048, d_out, nullptr, x);
}